// Round 10
// baseline (212.863 us; speedup 1.0000x reference)
//
#include <hip/hip_runtime.h>
#include <math.h>

#define BATCH 524288
#define VEC 512
#define TPR 128  // threads per row: each thread produces 2 (sin,cos) pairs = 1 float4

typedef float f32x4 __attribute__((ext_vector_type(4)));

// Accurate sincos of an f32 phase value: f64 reduction by pi/2 of the exact
// f32 input, then f32 minimax kernels on [-pi/4, pi/4] (~1e-7 abs error).
// (R2==R6 and R3==R5 bit-identical absmax proved sin impl is NOT the error
// source; all observed error is in the frequency values.)
__device__ __forceinline__ void sincos_acc(float phf, float& s, float& c) {
    const double two_over_pi = 0.6366197723675814;
    const double pio2        = 1.5707963267948966;
    const double ph  = (double)phf;                 // exact
    const double nd  = rint(ph * two_over_pi);      // |nd| <= ~3.4e4, exact int
    const double red = fma(-nd, pio2, ph);          // |red| <= pi/4, err ~1e-12
    const int    q   = ((int)nd) & 3;               // correct for negative nd
    const float  r   = (float)red;
    const float  r2  = r * r;
    float sp = fmaf(r2, 2.7183114939898219e-6f, -1.9839334836096632e-4f);
    sp = fmaf(r2, sp, 8.3333293858894632e-3f);
    sp = fmaf(r2, sp, -1.6666666641626524e-1f);
    sp = r * fmaf(r2, sp, 1.0f);
    float cp = fmaf(r2, 2.4390448796277409e-5f, -1.3886763774609929e-3f);
    cp = fmaf(r2, cp, 4.1666623323739063e-2f);
    cp = fmaf(r2, cp, -4.9999999725103100e-1f);
    cp = fmaf(r2, cp, 1.0f);
    const bool swp = (q & 1);
    float ss = swp ? cp : sp;
    float cc = swp ? sp : cp;
    s = (q & 2)       ? -ss : ss;
    c = ((q + 1) & 2) ? -cc : cc;
}

__global__ __launch_bounds__(256) void input_layer_kernel(const float* __restrict__ x,
                                                          float* __restrict__ out) {
    const int t = blockIdx.x * blockDim.x + threadIdx.x;
    const int q = t & (TPR - 1);         // which float4 within the row: 0..127
    const int row0 = t >> 7;             // starting row
    const int rows_per_step = (gridDim.x * blockDim.x) >> 7;

    // FREQUENCY MODEL (round 10): ref e-chain used FAST-MATH RECIPROCAL
    // division (XLA:CPU default fast-math, LLVM arcp):
    //   e = (i * fl32(1/255)) * 4     [NOT true f32 division i/255]
    // This differs from true division by ~1 ulp of i/255 -> Delta_e ~ 2.4e-7
    // -> ln10 * Delta_e * maxphase ~ 0.0265 == the measured 0.027/0.025
    // distance of R6/R5, and is ORTHOGONAL to all pow perturbations --
    // explaining why R7/R8/R9 (t-rounding ~+-0.012) landed at 0.039.
    // pow itself: ref = fast-math exp10f (modern glibc, double-internal,
    // <=1 ulp from CR) -> matched by correctly-rounded f64 pow here.
    const float RCP255 = 1.0f / 255.0f;                 // compile-time fl32(1/255)
    const float e0 = ((float)(2 * q)     * RCP255) * 4.0f;
    const float e1 = ((float)(2 * q + 1) * RCP255) * 4.0f;
    const float f0 = (float)pow(10.0, (double)e0);      // CR pow == CR powf
    const float f1 = (float)pow(10.0, (double)e1);

    for (int row = row0; row < BATCH; row += rows_per_step) {
        const float xv = x[row];
        float s0, c0, s1, c1;
        sincos_acc(xv * f0, s0, c0);     // phase rounded to f32, like the ref
        sincos_acc(xv * f1, s1, c1);
        // out[row, 4q .. 4q+3] = {sin(2q), cos(2q), sin(2q+1), cos(2q+1)}
        f32x4 o = {s0, c0, s1, c1};
        f32x4* dst = reinterpret_cast<f32x4*>(out + (size_t)row * VEC) + q;
        __builtin_nontemporal_store(o, dst);   // streaming: output never re-read
    }
}

extern "C" void kernel_launch(void* const* d_in, const int* in_sizes, int n_in,
                              void* d_out, int out_size, void* d_ws, size_t ws_size,
                              hipStream_t stream) {
    const float* x = (const float*)d_in[0];
    float* out = (float*)d_out;
    // 2048 blocks x 256 threads = 4096 rows per grid step, 128 grid-stride steps.
    input_layer_kernel<<<2048, 256, 0, stream>>>(x, out);
}